// Round 1
// baseline (435.950 us; speedup 1.0000x reference)
//
#include <hip/hip_runtime.h>
#include <stdint.h>

#define OUT_F 4096
#define IN_F  4096
#define NGROUPS 32

typedef __attribute__((ext_vector_type(4))) float    f32x4;
typedef __attribute__((ext_vector_type(8))) short    bf16x8;
typedef __attribute__((ext_vector_type(4))) int      i32x4;
typedef __attribute__((ext_vector_type(4))) uint32_t u32x4;

// round-to-nearest-even f32 -> bf16 (bit trick; NaN irrelevant for this data)
__device__ __forceinline__ ushort f2bf(float f) {
  union { float f; uint32_t u; } v; v.f = f;
  uint32_t r = v.u + 0x7FFFu + ((v.u >> 16) & 1u);
  return (ushort)(r >> 16);
}

// ---- kernel 1: x (f32) -> bf16, 8 elems/thread --------------------------
__global__ void cvt_x_kernel(const float* __restrict__ x, ushort* __restrict__ xb, int n8) {
  int i = blockIdx.x * blockDim.x + threadIdx.x;
  if (i >= n8) return;
  const f32x4* xp = (const f32x4*)x;
  f32x4 a = xp[2 * i], b = xp[2 * i + 1];
  u32x4 o;
  o.x = (uint32_t)f2bf(a.x) | ((uint32_t)f2bf(a.y) << 16);
  o.y = (uint32_t)f2bf(a.z) | ((uint32_t)f2bf(a.w) << 16);
  o.z = (uint32_t)f2bf(b.x) | ((uint32_t)f2bf(b.y) << 16);
  o.w = (uint32_t)f2bf(b.z) | ((uint32_t)f2bf(b.w) << 16);
  ((u32x4*)xb)[i] = o;
}

// ---- kernel 2: dequant weight -> bf16 [OUT_F][IN_F], 8 elems/thread -----
__global__ void dequant_w_kernel(const int* __restrict__ cw,
                                 const float* __restrict__ sc,
                                 const float* __restrict__ of,
                                 ushort* __restrict__ wb) {
  int t = blockIdx.x * blockDim.x + threadIdx.x;   // 0 .. OUT_F*IN_F/8
  int o  = t >> 9;                 // 512 threads per output row
  int k0 = (t & 511) << 3;         // 8 consecutive k, same group (8 | 128)
  int g  = k0 >> 7;
  float s   = sc[o * NGROUPS + g];
  float off = of[o * NGROUPS + g];
  const i32x4* cp = (const i32x4*)(cw + (size_t)o * IN_F + k0);
  i32x4 c0 = cp[0], c1 = cp[1];
  u32x4 out;
  out.x = (uint32_t)f2bf((float)c0.x * s - off) | ((uint32_t)f2bf((float)c0.y * s - off) << 16);
  out.y = (uint32_t)f2bf((float)c0.z * s - off) | ((uint32_t)f2bf((float)c0.w * s - off) << 16);
  out.z = (uint32_t)f2bf((float)c1.x * s - off) | ((uint32_t)f2bf((float)c1.y * s - off) << 16);
  out.w = (uint32_t)f2bf((float)c1.z * s - off) | ((uint32_t)f2bf((float)c1.w * s - off) << 16);
  *(u32x4*)(wb + (size_t)o * IN_F + k0) = out;
}

// ---- kernel 3: bf16 GEMM, C[M][N] = A[M][K] * B[N][K]^T  (m97 structure)
// 128x128 tile, BK=32, 4 waves (2x2), each wave 64x64 via 4x4 frags of
// mfma_f32_16x16x32_bf16. global_load_lds width=16, linear LDS.
__global__ __launch_bounds__(256) void gemm_kernel(
    const ushort* __restrict__ A,   // [M][IN_F] bf16
    const ushort* __restrict__ B,   // [OUT_F][IN_F] bf16 (i.e. B^T layout)
    float* __restrict__ C, int M) {
  __shared__ ushort As[128 * 32];
  __shared__ ushort Bs[128 * 32];

  const int bid = blockIdx.x;
  const int bm = bid >> 5;              // N tiles = 4096/128 = 32
  const int bn = bid & 31;
  const int m0 = bm << 7, n0 = bn << 7;

  const int tid  = threadIdx.x;
  const int lane = tid & 63;
  const int wid  = tid >> 6;
  const int wm = (wid >> 1) << 6;       // wave sub-tile origin in tile
  const int wn = (wid & 1) << 6;

  // staging geometry: wave wid stages LDS chunks {2*wid, 2*wid+1}, 1024B each.
  // lane l covers row (chunk*16 + l/4), k-bytes (l%4)*16  -> linear lane*16.
  const int rowA = (wid << 5) + (lane >> 2);   // + c*16 per call
  const int colk = (lane & 3) << 3;            // bf16 elems
  const ushort* aSrc = A + (size_t)(m0 + rowA) * IN_F + colk;
  const ushort* bSrc = B + (size_t)(n0 + rowA) * IN_F + colk;

  // fragment-read geometry (A/B frag: row|col = lane&15, k = (lane>>4)*8)
  const int fr = lane & 15;
  const int fk = (lane >> 4) << 3;

  f32x4 acc[4][4] = {};

  for (int k0 = 0; k0 < IN_F; k0 += 32) {
#pragma unroll
    for (int c = 0; c < 2; ++c) {
      __builtin_amdgcn_global_load_lds(
          (const __attribute__((address_space(1))) uint32_t*)(const void*)(aSrc + (size_t)c * 16 * IN_F + k0),
          (__attribute__((address_space(3))) uint32_t*)(void*)(As + ((wid << 5) + (c << 4)) * 32),
          16, 0, 0);
      __builtin_amdgcn_global_load_lds(
          (const __attribute__((address_space(1))) uint32_t*)(const void*)(bSrc + (size_t)c * 16 * IN_F + k0),
          (__attribute__((address_space(3))) uint32_t*)(void*)(Bs + ((wid << 5) + (c << 4)) * 32),
          16, 0, 0);
    }
    __syncthreads();

    bf16x8 af[4], bf[4];
#pragma unroll
    for (int i = 0; i < 4; ++i) {
      af[i] = *(const bf16x8*)(As + (wm + i * 16 + fr) * 32 + fk);
      bf[i] = *(const bf16x8*)(Bs + (wn + i * 16 + fr) * 32 + fk);
    }
#pragma unroll
    for (int i = 0; i < 4; ++i)
#pragma unroll
      for (int j = 0; j < 4; ++j)
        acc[i][j] = __builtin_amdgcn_mfma_f32_16x16x32_bf16(af[i], bf[j], acc[i][j], 0, 0, 0);
    __syncthreads();
  }

  // epilogue: C/D layout col=lane&15, row=(lane>>4)*4+reg  [m89-verified]
  const int crow0 = m0 + wm + ((lane >> 4) << 2);
  const int ccol0 = n0 + wn + fr;
#pragma unroll
  for (int i = 0; i < 4; ++i)
#pragma unroll
    for (int j = 0; j < 4; ++j)
#pragma unroll
      for (int q = 0; q < 4; ++q)
        C[(size_t)(crow0 + i * 16 + q) * OUT_F + (ccol0 + j * 16)] = acc[i][j][q];
}

// ---- fallback (only if ws too small): naive f32, correct but slow ------
__global__ void naive_kernel(const float* __restrict__ x, const int* __restrict__ cw,
                             const float* __restrict__ sc, const float* __restrict__ of,
                             float* __restrict__ out, int M) {
  int idx = blockIdx.x * blockDim.x + threadIdx.x;
  if (idx >= M * OUT_F) return;
  int o = idx & (OUT_F - 1);
  int m = idx >> 12;
  const float* xr = x + (size_t)m * IN_F;
  const int*   wr = cw + (size_t)o * IN_F;
  float acc = 0.f;
  for (int g = 0; g < NGROUPS; ++g) {
    float s = sc[o * NGROUPS + g], off = of[o * NGROUPS + g];
#pragma unroll 8
    for (int k = 0; k < 128; ++k) {
      int kk = (g << 7) + k;
      acc += xr[kk] * ((float)wr[kk] * s - off);
    }
  }
  out[idx] = acc;
}

extern "C" void kernel_launch(void* const* d_in, const int* in_sizes, int n_in,
                              void* d_out, int out_size, void* d_ws, size_t ws_size,
                              hipStream_t stream) {
  const float* x  = (const float*)d_in[0];
  const int*   cw = (const int*)d_in[1];
  const float* sc = (const float*)d_in[2];
  const float* of = (const float*)d_in[3];
  float* out = (float*)d_out;
  const int M = in_sizes[0] / IN_F;   // 8192

  const size_t xb_bytes = (size_t)M * IN_F * 2;
  const size_t wb_bytes = (size_t)OUT_F * IN_F * 2;

  if (ws_size >= xb_bytes + wb_bytes && (M % 128) == 0) {
    ushort* xb = (ushort*)d_ws;
    ushort* wb = (ushort*)((char*)d_ws + xb_bytes);

    int n8 = (M * IN_F) / 8;
    cvt_x_kernel<<<(n8 + 255) / 256, 256, 0, stream>>>(x, xb, n8);

    int nw8 = (OUT_F * IN_F) / 8;
    dequant_w_kernel<<<(nw8 + 255) / 256, 256, 0, stream>>>(cw, sc, of, wb);

    dim3 grid((M / 128) * (OUT_F / 128));   // 64 * 32 = 2048
    gemm_kernel<<<grid, 256, 0, stream>>>(xb, wb, out, M);
  } else {
    int total = M * OUT_F;
    naive_kernel<<<(total + 255) / 256, 256, 0, stream>>>(x, cw, sc, of, out, M);
  }
}

// Round 2
// 300.950 us; speedup vs baseline: 1.4486x; 1.4486x over previous
//
#include <hip/hip_runtime.h>
#include <stdint.h>

#define OUT_F 4096
#define IN_F  4096
#define NGROUPS 32
#define BK 64
#define NT (IN_F / BK)   // 64

typedef __attribute__((ext_vector_type(4))) float    f32x4;
typedef __attribute__((ext_vector_type(8))) short    bf16x8;
typedef __attribute__((ext_vector_type(4))) int      i32x4;
typedef __attribute__((ext_vector_type(4))) uint32_t u32x4;

__device__ __forceinline__ ushort f2bf(float f) {
  union { float f; uint32_t u; } v; v.f = f;
  uint32_t r = v.u + 0x7FFFu + ((v.u >> 16) & 1u);
  return (ushort)(r >> 16);
}

// ---- kernel 1: x (f32) -> bf16, 8 elems/thread --------------------------
__global__ void cvt_x_kernel(const float* __restrict__ x, ushort* __restrict__ xb, int n8) {
  int i = blockIdx.x * blockDim.x + threadIdx.x;
  if (i >= n8) return;
  const f32x4* xp = (const f32x4*)x;
  f32x4 a = xp[2 * i], b = xp[2 * i + 1];
  u32x4 o;
  o.x = (uint32_t)f2bf(a.x) | ((uint32_t)f2bf(a.y) << 16);
  o.y = (uint32_t)f2bf(a.z) | ((uint32_t)f2bf(a.w) << 16);
  o.z = (uint32_t)f2bf(b.x) | ((uint32_t)f2bf(b.y) << 16);
  o.w = (uint32_t)f2bf(b.z) | ((uint32_t)f2bf(b.w) << 16);
  ((u32x4*)xb)[i] = o;
}

// ---- kernel 2: dequant weight -> bf16 [OUT_F][IN_F] ----------------------
__global__ void dequant_w_kernel(const int* __restrict__ cw,
                                 const float* __restrict__ sc,
                                 const float* __restrict__ of,
                                 ushort* __restrict__ wb) {
  int t = blockIdx.x * blockDim.x + threadIdx.x;
  int o  = t >> 9;
  int k0 = (t & 511) << 3;
  int g  = k0 >> 7;
  float s   = sc[o * NGROUPS + g];
  float off = of[o * NGROUPS + g];
  const i32x4* cp = (const i32x4*)(cw + (size_t)o * IN_F + k0);
  i32x4 c0 = cp[0], c1 = cp[1];
  u32x4 out;
  out.x = (uint32_t)f2bf((float)c0.x * s - off) | ((uint32_t)f2bf((float)c0.y * s - off) << 16);
  out.y = (uint32_t)f2bf((float)c0.z * s - off) | ((uint32_t)f2bf((float)c0.w * s - off) << 16);
  out.z = (uint32_t)f2bf((float)c1.x * s - off) | ((uint32_t)f2bf((float)c1.y * s - off) << 16);
  out.w = (uint32_t)f2bf((float)c1.z * s - off) | ((uint32_t)f2bf((float)c1.w * s - off) << 16);
  *(u32x4*)(wb + (size_t)o * IN_F + k0) = out;
}

// ---- kernel 3: 256x256 tile, BK=64, 8-wave, 8-phase-style pipelined GEMM
// C[M][N] = A[M][K] * B[N][K]^T, all bf16 in, f32 out.
// LDS 128KB: [buf(2)][mat(2:A,B)][half(2)][128 rows][8 slots of 16B]
// swizzle: slot_lds = slot_logical ^ (row & 7), staged via pre-swizzled global src.

#define BAR() do { asm volatile("" ::: "memory"); __builtin_amdgcn_s_barrier(); asm volatile("" ::: "memory"); } while (0)

#define GLLDS(gp, lp) __builtin_amdgcn_global_load_lds( \
  (const __attribute__((address_space(1))) uint32_t*)(const void*)(gp), \
  (__attribute__((address_space(3))) uint32_t*)(void*)(lp), 16, 0, 0)

#define STAGE_A(buf, kt) do { \
  _Pragma("unroll") for (int h_ = 0; h_ < 2; ++h_) \
  _Pragma("unroll") for (int c_ = 0; c_ < 2; ++c_) \
    GLLDS(A + (size_t)(m0 + h_ * 128 + c_ * 64 + stRow) * IN_F + (kt) * BK + sl * 8, \
          ldsb + (buf) * 65536 + h_ * 16384 + c_ * 8192 + wid * 1024); \
} while (0)

#define STAGE_B_HALF(buf, kt, h_) do { \
  _Pragma("unroll") for (int c_ = 0; c_ < 2; ++c_) \
    GLLDS(B + (size_t)(n0 + (h_) * 128 + c_ * 64 + stRow) * IN_F + (kt) * BK + sl * 8, \
          ldsb + (buf) * 65536 + 32768 + (h_) * 16384 + c_ * 8192 + wid * 1024); \
} while (0)

#define MFMA8(I0, J0) do { \
  _Pragma("unroll") for (int i_ = 0; i_ < 4; ++i_) \
  _Pragma("unroll") for (int j_ = 0; j_ < 2; ++j_) { \
    acc[(I0) + i_][(J0) + j_] = __builtin_amdgcn_mfma_f32_16x16x32_bf16(Ar[i_][0], Br[(J0) + j_][0], acc[(I0) + i_][(J0) + j_], 0, 0, 0); \
    acc[(I0) + i_][(J0) + j_] = __builtin_amdgcn_mfma_f32_16x16x32_bf16(Ar[i_][1], Br[(J0) + j_][1], acc[(I0) + i_][(J0) + j_], 0, 0, 0); \
  } } while (0)

__global__ __launch_bounds__(512, 2) void gemm256(const ushort* __restrict__ A,
                                                  const ushort* __restrict__ B,
                                                  float* __restrict__ C, int M) {
  __shared__ ushort lds[65536];   // 128 KiB
  char* ldsb = (char*)lds;

  const int nmt = M >> 8;                    // M tiles (32)
  const int nwg = gridDim.x;
  int wg = blockIdx.x;
  if ((nwg & 7) == 0) wg = (wg & 7) * (nwg >> 3) + (wg >> 3);   // XCD swizzle (bijective)
  const int bn = wg / nmt;                   // each XCD: contiguous bn chunk -> B panel L2-resident
  const int bm = wg % nmt;
  const int m0 = bm << 8, n0 = bn << 8;

  const int tid  = threadIdx.x;
  const int lane = tid & 63;
  const int wid  = tid >> 6;                 // 0..7
  const int wr   = wid >> 2;                 // 0..1  (A half)
  const int wc   = wid & 3;                  // 0..3  (B 64-row stripe)

  // staging geometry (per thread): row within 64-row quarter, pre-swizzled slot
  const int stRow = wid * 8 + (lane >> 3);   // + h*128 + c*64
  const int sl    = (lane & 7) ^ (lane >> 3);

  // fragment-read geometry
  const int frow = lane & 15;
  const int g    = lane >> 4;
  const int off0 = frow * 128 + (((g    ) ^ (lane & 7)) << 4);  // kk=0
  const int off1 = frow * 128 + (((4 + g) ^ (lane & 7)) << 4);  // kk=1

  f32x4 acc[8][4] = {};
  bf16x8 Ar[4][2], Br[4][2];

  // ---- prologue: stage A(0), B(0), A(1); wait A(0)+B(0) (leave A(1) in flight)
  STAGE_A(0, 0);
  STAGE_B_HALF(0, 0, 0);
  STAGE_B_HALF(0, 0, 1);
  STAGE_A(1, 1);
  asm volatile("s_waitcnt vmcnt(4)" ::: "memory");
  BAR();

#pragma unroll 1
  for (int t = 0; t < NT; ++t) {
    const int cur = t & 1, nxt = cur ^ 1;
    const char* aB = ldsb + cur * 65536 + wr * 16384;
    const char* bB = ldsb + cur * 65536 + 32768 + (wc >> 1) * 16384 + (wc & 1) * 8192;

    // ---- phase 0: read A mf0-3 + B nf0-1; stage B(t+1) half0; MFMA (mf0-3 x nf0-1)
#pragma unroll
    for (int i = 0; i < 4; ++i) {
      Ar[i][0] = *(const bf16x8*)(aB + i * 2048 + off0);
      Ar[i][1] = *(const bf16x8*)(aB + i * 2048 + off1);
    }
#pragma unroll
    for (int j = 0; j < 2; ++j) {
      Br[j][0] = *(const bf16x8*)(bB + j * 2048 + off0);
      Br[j][1] = *(const bf16x8*)(bB + j * 2048 + off1);
    }
    if (t + 1 < NT) STAGE_B_HALF(nxt, t + 1, 0);
    BAR();
    __builtin_amdgcn_s_setprio(1);
    MFMA8(0, 0);
    __builtin_amdgcn_s_setprio(0);
    BAR();

    // ---- phase 1: read B nf2-3; stage B(t+1) half1; MFMA (mf0-3 x nf2-3)
#pragma unroll
    for (int j = 2; j < 4; ++j) {
      Br[j][0] = *(const bf16x8*)(bB + j * 2048 + off0);
      Br[j][1] = *(const bf16x8*)(bB + j * 2048 + off1);
    }
    if (t + 1 < NT) STAGE_B_HALF(nxt, t + 1, 1);
    BAR();
    __builtin_amdgcn_s_setprio(1);
    MFMA8(0, 2);
    __builtin_amdgcn_s_setprio(0);
    BAR();

    // ---- phase 2: read A mf4-7; MFMA (mf4-7 x nf2-3)
#pragma unroll
    for (int i = 0; i < 4; ++i) {
      Ar[i][0] = *(const bf16x8*)(aB + (4 + i) * 2048 + off0);
      Ar[i][1] = *(const bf16x8*)(aB + (4 + i) * 2048 + off1);
    }
    BAR();
    __builtin_amdgcn_s_setprio(1);
    MFMA8(4, 2);
    __builtin_amdgcn_s_setprio(0);
    BAR();

    // ---- phase 3: stage A(t+2) into cur (A(t) fully read at p2); MFMA (mf4-7 x nf0-1);
    //      counted vmcnt (leaves A(t+2) in flight) before the K-tile switch barrier.
    if (t + 2 < NT) STAGE_A(cur, t + 2);
    BAR();
    __builtin_amdgcn_s_setprio(1);
    MFMA8(4, 0);
    __builtin_amdgcn_s_setprio(0);
    if (t + 2 < NT) { asm volatile("s_waitcnt vmcnt(4)" ::: "memory"); }
    else            { asm volatile("s_waitcnt vmcnt(0)" ::: "memory"); }
    BAR();
  }

  // ---- epilogue: C/D layout col=lane&15, row=(lane>>4)*4+reg [m89-verified]
  const int crow0 = m0 + wr * 128 + (g << 2);
  const int ccol0 = n0 + wc * 64 + frow;
#pragma unroll
  for (int mf = 0; mf < 8; ++mf)
#pragma unroll
    for (int nf = 0; nf < 4; ++nf)
#pragma unroll
      for (int q = 0; q < 4; ++q)
        C[(size_t)(crow0 + mf * 16 + q) * OUT_F + (ccol0 + nf * 16)] = acc[mf][nf][q];
}

// ---- fallback: naive f32, correct but slow ------------------------------
__global__ void naive_kernel(const float* __restrict__ x, const int* __restrict__ cw,
                             const float* __restrict__ sc, const float* __restrict__ of,
                             float* __restrict__ out, int M) {
  int idx = blockIdx.x * blockDim.x + threadIdx.x;
  if (idx >= M * OUT_F) return;
  int o = idx & (OUT_F - 1);
  int m = idx >> 12;
  const float* xr = x + (size_t)m * IN_F;
  const int*   wr = cw + (size_t)o * IN_F;
  float acc = 0.f;
  for (int gg = 0; gg < NGROUPS; ++gg) {
    float s = sc[o * NGROUPS + gg], off = of[o * NGROUPS + gg];
#pragma unroll 8
    for (int k = 0; k < 128; ++k) {
      int kk = (gg << 7) + k;
      acc += xr[kk] * ((float)wr[kk] * s - off);
    }
  }
  out[idx] = acc;
}

extern "C" void kernel_launch(void* const* d_in, const int* in_sizes, int n_in,
                              void* d_out, int out_size, void* d_ws, size_t ws_size,
                              hipStream_t stream) {
  const float* x  = (const float*)d_in[0];
  const int*   cw = (const int*)d_in[1];
  const float* sc = (const float*)d_in[2];
  const float* of = (const float*)d_in[3];
  float* out = (float*)d_out;
  const int M = in_sizes[0] / IN_F;   // 8192

  const size_t xb_bytes = (size_t)M * IN_F * 2;
  const size_t wb_bytes = (size_t)OUT_F * IN_F * 2;

  if (ws_size >= xb_bytes + wb_bytes && (M % 256) == 0) {
    ushort* xb = (ushort*)d_ws;
    ushort* wb = (ushort*)((char*)d_ws + xb_bytes);

    int n8 = (M * IN_F) / 8;
    cvt_x_kernel<<<(n8 + 255) / 256, 256, 0, stream>>>(x, xb, n8);

    int nw8 = (OUT_F * IN_F) / 8;
    dequant_w_kernel<<<(nw8 + 255) / 256, 256, 0, stream>>>(cw, sc, of, wb);

    dim3 grid((M / 256) * (OUT_F / 256));   // 32 * 16 = 512
    gemm256<<<grid, 512, 0, stream>>>(xb, wb, out, M);
  } else {
    int total = M * OUT_F;
    naive_kernel<<<(total + 255) / 256, 256, 0, stream>>>(x, cw, sc, of, out, M);
  }
}

// Round 3
// 290.995 us; speedup vs baseline: 1.4981x; 1.0342x over previous
//
#include <hip/hip_runtime.h>
#include <stdint.h>

#define OUT_F 4096
#define IN_F  4096
#define NGROUPS 32
#define BK 64
#define NT (IN_F / BK)   // 64

typedef __attribute__((ext_vector_type(4))) float    f32x4;
typedef __attribute__((ext_vector_type(8))) short    bf16x8;
typedef __attribute__((ext_vector_type(4))) int      i32x4;
typedef __attribute__((ext_vector_type(4))) uint32_t u32x4;

__device__ __forceinline__ ushort f2bf(float f) {
  union { float f; uint32_t u; } v; v.f = f;
  uint32_t r = v.u + 0x7FFFu + ((v.u >> 16) & 1u);
  return (ushort)(r >> 16);
}

// ---- kernel 1: x (f32) -> bf16, 8 elems/thread --------------------------
__global__ void cvt_x_kernel(const float* __restrict__ x, ushort* __restrict__ xb, int n8) {
  int i = blockIdx.x * blockDim.x + threadIdx.x;
  if (i >= n8) return;
  const f32x4* xp = (const f32x4*)x;
  f32x4 a = xp[2 * i], b = xp[2 * i + 1];
  u32x4 o;
  o.x = (uint32_t)f2bf(a.x) | ((uint32_t)f2bf(a.y) << 16);
  o.y = (uint32_t)f2bf(a.z) | ((uint32_t)f2bf(a.w) << 16);
  o.z = (uint32_t)f2bf(b.x) | ((uint32_t)f2bf(b.y) << 16);
  o.w = (uint32_t)f2bf(b.z) | ((uint32_t)f2bf(b.w) << 16);
  ((u32x4*)xb)[i] = o;
}

// ---- kernel 2: dequant weight -> bf16 [OUT_F][IN_F] ----------------------
__global__ void dequant_w_kernel(const int* __restrict__ cw,
                                 const float* __restrict__ sc,
                                 const float* __restrict__ of,
                                 ushort* __restrict__ wb) {
  int t = blockIdx.x * blockDim.x + threadIdx.x;
  int o  = t >> 9;
  int k0 = (t & 511) << 3;
  int g  = k0 >> 7;
  float s   = sc[o * NGROUPS + g];
  float off = of[o * NGROUPS + g];
  const i32x4* cp = (const i32x4*)(cw + (size_t)o * IN_F + k0);
  i32x4 c0 = cp[0], c1 = cp[1];
  u32x4 out;
  out.x = (uint32_t)f2bf((float)c0.x * s - off) | ((uint32_t)f2bf((float)c0.y * s - off) << 16);
  out.y = (uint32_t)f2bf((float)c0.z * s - off) | ((uint32_t)f2bf((float)c0.w * s - off) << 16);
  out.z = (uint32_t)f2bf((float)c1.x * s - off) | ((uint32_t)f2bf((float)c1.y * s - off) << 16);
  out.w = (uint32_t)f2bf((float)c1.z * s - off) | ((uint32_t)f2bf((float)c1.w * s - off) << 16);
  *(u32x4*)(wb + (size_t)o * IN_F + k0) = out;
}

// ---- kernel 3: 256x256 tile, BK=64, 8-wave pipelined GEMM ---------------
// C[M][N] = A[M][K] * B[N][K]^T, bf16 in, f32 out.
// LDS 128KB: [buf(2)][mat(2:A,B)][half(2)][128 rows][8 slots of 16B]
// swizzle: slot_lds = slot ^ (row & 7) via pre-swizzled global source.
// Register-neutral pipelining: A-quadrant reads issued AFTER the MFMA
// cluster that last consumes the same registers (lead >= 1 phase).

#define BAR() do { asm volatile("" ::: "memory"); __builtin_amdgcn_s_barrier(); asm volatile("" ::: "memory"); } while (0)

#define GLLDS(gp, lp) __builtin_amdgcn_global_load_lds( \
  (const __attribute__((address_space(1))) uint32_t*)(const void*)(gp), \
  (__attribute__((address_space(3))) uint32_t*)(void*)(lp), 16, 0, 0)

#define STAGE_A(buf, kt) do { \
  _Pragma("unroll") for (int h_ = 0; h_ < 2; ++h_) \
  _Pragma("unroll") for (int c_ = 0; c_ < 2; ++c_) \
    GLLDS(A + (size_t)(m0 + h_ * 128 + c_ * 64 + stRow) * IN_F + (kt) * BK + sl * 8, \
          ldsb + (buf) * 65536 + h_ * 16384 + c_ * 8192 + wid * 1024); \
} while (0)

#define STAGE_B_HALF(buf, kt, h_) do { \
  _Pragma("unroll") for (int c_ = 0; c_ < 2; ++c_) \
    GLLDS(B + (size_t)(n0 + (h_) * 128 + c_ * 64 + stRow) * IN_F + (kt) * BK + sl * 8, \
          ldsb + (buf) * 65536 + 32768 + (h_) * 16384 + c_ * 8192 + wid * 1024); \
} while (0)

#define RD_A(base, i0) do { \
  _Pragma("unroll") for (int i_ = 0; i_ < 4; ++i_) { \
    Ar[i_][0] = *(const bf16x8*)((base) + ((i0) + i_) * 2048 + off0); \
    Ar[i_][1] = *(const bf16x8*)((base) + ((i0) + i_) * 2048 + off1); \
  } } while (0)

#define RD_B(dst, j0) do { \
  _Pragma("unroll") for (int j_ = 0; j_ < 2; ++j_) { \
    dst[j_][0] = *(const bf16x8*)(bC + ((j0) + j_) * 2048 + off0); \
    dst[j_][1] = *(const bf16x8*)(bC + ((j0) + j_) * 2048 + off1); \
  } } while (0)

#define MFMAQ(I0, J0, Bset) do { \
  __builtin_amdgcn_s_setprio(1); \
  _Pragma("unroll") for (int i_ = 0; i_ < 4; ++i_) \
  _Pragma("unroll") for (int j_ = 0; j_ < 2; ++j_) { \
    acc[(I0) + i_][(J0) + j_] = __builtin_amdgcn_mfma_f32_16x16x32_bf16(Ar[i_][0], Bset[j_][0], acc[(I0) + i_][(J0) + j_], 0, 0, 0); \
    acc[(I0) + i_][(J0) + j_] = __builtin_amdgcn_mfma_f32_16x16x32_bf16(Ar[i_][1], Bset[j_][1], acc[(I0) + i_][(J0) + j_], 0, 0, 0); \
  } \
  __builtin_amdgcn_s_setprio(0); \
} while (0)

__global__ __launch_bounds__(512, 2) void gemm256(const ushort* __restrict__ A,
                                                  const ushort* __restrict__ B,
                                                  float* __restrict__ C, int M) {
  __shared__ ushort lds[65536];   // 128 KiB
  char* ldsb = (char*)lds;

  const int nmt = M >> 8;                    // M tiles (32)
  const int nwg = gridDim.x;
  int wg = blockIdx.x;
  if ((nwg & 7) == 0) wg = (wg & 7) * (nwg >> 3) + (wg >> 3);   // XCD swizzle (bijective)
  const int bn = wg / nmt;
  const int bm = wg % nmt;
  const int m0 = bm << 8, n0 = bn << 8;

  const int tid  = threadIdx.x;
  const int lane = tid & 63;
  const int wid  = tid >> 6;                 // 0..7
  const int wr   = wid >> 2;                 // 0..1  (A half)
  const int wc   = wid & 3;                  // 0..3  (B 64-row stripe)

  const int stRow = wid * 8 + (lane >> 3);
  const int sl    = (lane & 7) ^ (lane >> 3);

  const int frow = lane & 15;
  const int g    = lane >> 4;
  const int off0 = frow * 128 + (((g    ) ^ (lane & 7)) << 4);
  const int off1 = frow * 128 + (((4 + g) ^ (lane & 7)) << 4);

  f32x4 acc[8][4] = {};
  bf16x8 Ar[4][2], Bl[2][2], Bh[2][2];

  // ---- prologue: stage A(0)+B(0)+A(1); publish A(0),B(0); preload Alo(0)
  STAGE_A(0, 0);
  STAGE_B_HALF(0, 0, 0);
  STAGE_B_HALF(0, 0, 1);
  STAGE_A(1, 1);
  asm volatile("s_waitcnt vmcnt(4)" ::: "memory");
  BAR();
  RD_A(ldsb + wr * 16384, 0);     // Alo(0), lead-1 for Q00(0)

#pragma unroll 1
  for (int t = 0; t < NT; ++t) {
    const int cur = t & 1, nxt = cur ^ 1;
    const char* aC = ldsb + cur * 65536 + wr * 16384;
    const char* aN = ldsb + nxt * 65536 + wr * 16384;
    const char* bC = ldsb + cur * 65536 + 32768 + (wc >> 1) * 16384 + (wc & 1) * 8192;

    // ---- p0: read B(t); stage B(t+1)h0; MFMA Q00 (Alo x Bl)
    RD_B(Bl, 0);
    RD_B(Bh, 2);
    if (t + 1 < NT) STAGE_B_HALF(nxt, t + 1, 0);
    BAR();                                   // alpha
    MFMAQ(0, 0, Bl);

    // ---- p1: stage B(t+1)h1; MFMA Q01 (Alo x Bh); post-read Ahi(t);
    //          vmcnt(4)+BAR publishes A(t+1)
    if (t + 1 < NT) STAGE_B_HALF(nxt, t + 1, 1);
    BAR();                                   // beta
    MFMAQ(0, 2, Bh);
    RD_A(aC, 4);                             // Ahi(t), lead-1 for Q11
    if (t + 1 < NT) { asm volatile("s_waitcnt vmcnt(4)" ::: "memory"); }
    BAR();                                   // gamma (publishes A(t+1))

    // ---- p2: MFMA Q11 (Ahi x Bh)
    MFMAQ(4, 2, Bh);
    BAR();                                   // delta (A(t) reads done -> safe to restage)

    // ---- p3: stage A(t+2) overlapped with MFMA Q10 (Ahi x Bl);
    //          post-read Alo(t+1) from nxt; vmcnt publishes B(t+1)
    if (t + 2 < NT) STAGE_A(cur, t + 2);
    MFMAQ(4, 0, Bl);
    if (t + 1 < NT) {
      RD_A(aN, 0);                           // Alo(t+1), lead-1 for Q00(t+1)
      if (t + 2 < NT) { asm volatile("s_waitcnt vmcnt(4)" ::: "memory"); }
      else            { asm volatile("s_waitcnt vmcnt(0)" ::: "memory"); }
    }
    BAR();                                   // epsilon (publishes B(t+1))
  }

  // ---- epilogue: C/D layout col=lane&15, row=(lane>>4)*4+reg [m89-verified]
  const int crow0 = m0 + wr * 128 + (g << 2);
  const int ccol0 = n0 + wc * 64 + frow;
#pragma unroll
  for (int mf = 0; mf < 8; ++mf)
#pragma unroll
    for (int nf = 0; nf < 4; ++nf)
#pragma unroll
      for (int q = 0; q < 4; ++q)
        C[(size_t)(crow0 + mf * 16 + q) * OUT_F + (ccol0 + nf * 16)] = acc[mf][nf][q];
}

// ---- fallback: naive f32, correct but slow ------------------------------
__global__ void naive_kernel(const float* __restrict__ x, const int* __restrict__ cw,
                             const float* __restrict__ sc, const float* __restrict__ of,
                             float* __restrict__ out, int M) {
  int idx = blockIdx.x * blockDim.x + threadIdx.x;
  if (idx >= M * OUT_F) return;
  int o = idx & (OUT_F - 1);
  int m = idx >> 12;
  const float* xr = x + (size_t)m * IN_F;
  const int*   wr = cw + (size_t)o * IN_F;
  float acc = 0.f;
  for (int gg = 0; gg < NGROUPS; ++gg) {
    float s = sc[o * NGROUPS + gg], off = of[o * NGROUPS + gg];
#pragma unroll 8
    for (int k = 0; k < 128; ++k) {
      int kk = (gg << 7) + k;
      acc += xr[kk] * ((float)wr[kk] * s - off);
    }
  }
  out[idx] = acc;
}

extern "C" void kernel_launch(void* const* d_in, const int* in_sizes, int n_in,
                              void* d_out, int out_size, void* d_ws, size_t ws_size,
                              hipStream_t stream) {
  const float* x  = (const float*)d_in[0];
  const int*   cw = (const int*)d_in[1];
  const float* sc = (const float*)d_in[2];
  const float* of = (const float*)d_in[3];
  float* out = (float*)d_out;
  const int M = in_sizes[0] / IN_F;   // 8192

  const size_t xb_bytes = (size_t)M * IN_F * 2;
  const size_t wb_bytes = (size_t)OUT_F * IN_F * 2;

  if (ws_size >= xb_bytes + wb_bytes && (M % 256) == 0) {
    ushort* xb = (ushort*)d_ws;
    ushort* wb = (ushort*)((char*)d_ws + xb_bytes);

    int n8 = (M * IN_F) / 8;
    cvt_x_kernel<<<(n8 + 255) / 256, 256, 0, stream>>>(x, xb, n8);

    int nw8 = (OUT_F * IN_F) / 8;
    dequant_w_kernel<<<(nw8 + 255) / 256, 256, 0, stream>>>(cw, sc, of, wb);

    dim3 grid((M / 256) * (OUT_F / 256));   // 32 * 16 = 512
    gemm256<<<grid, 512, 0, stream>>>(xb, wb, out, M);
  } else {
    int total = M * OUT_F;
    naive_kernel<<<(total + 255) / 256, 256, 0, stream>>>(x, cw, sc, of, out, M);
  }
}